// Round 5
// baseline (261.875 us; speedup 1.0000x reference)
//
#include <hip/hip_runtime.h>
#include <math.h>

#define NTOK   262144
#define DIM    1024
#define NEXP   64
#define TOPK   8
#define WROWS  16           // rows per wave
#define ROWS   128          // rows per block = 8 waves x 16 rows
#define BLK    512
#define BKF    64           // K-slab in floats (256 B per row), = 2 MFMA K-steps
#define NSLAB  (DIM / BKF)  // 16 slabs
#define SLICE  8192         // per-wave LDS: 2 x 4KB stage dbuf (scores alias)

#define OFF_IDX ((size_t)NTOK * TOPK)
#define OFF_USE (2 * (size_t)NTOK * TOPK)
#define OFF_TOT (OFF_USE + NEXP)

typedef __attribute__((ext_vector_type(8))) short bf16x8;
typedef __attribute__((ext_vector_type(4))) float f32x4;

union FragU { bf16x8 v; unsigned int u[4]; };

// pack 8 f32 (a=k0..3, b=k4..7) -> bf16x8 fragment (truncate)
__device__ __forceinline__ bf16x8 pack_bf16(float4 a, float4 b) {
    FragU r;
    r.u[0] = (__float_as_uint(a.x) >> 16) | (__float_as_uint(a.y) & 0xFFFF0000u);
    r.u[1] = (__float_as_uint(a.z) >> 16) | (__float_as_uint(a.w) & 0xFFFF0000u);
    r.u[2] = (__float_as_uint(b.x) >> 16) | (__float_as_uint(b.y) & 0xFFFF0000u);
    r.u[3] = (__float_as_uint(b.z) >> 16) | (__float_as_uint(b.w) & 0xFFFF0000u);
    return r.v;
}

// W [64][1024] f32 -> bf16 MFMA B-fragments in d_ws:
//   wf[((kc*4+nt)*64 + lane)*8 + j] = bf16(W[nt*16+(lane&15)][kc*32+(lane>>4)*8+j])
// kc = global K-step (0..31). Also init usage counters + total_tokens.
__global__ __launch_bounds__(256) void gate_prep_kernel(const float* __restrict__ W,
                                                        unsigned short* __restrict__ wf,
                                                        float* __restrict__ out) {
    int idx = blockIdx.x * 256 + threadIdx.x;      // 65536 total
    int j    = idx & 7;
    int lane = (idx >> 3) & 63;
    int nt   = (idx >> 9) & 3;
    int kc   = idx >> 11;
    int fq = lane >> 4, fr = lane & 15;
    float v = W[(size_t)(nt * 16 + fr) * DIM + kc * 32 + fq * 8 + j];
    unsigned int u = __float_as_uint(v);
    u += 0x7FFFu + ((u >> 16) & 1u);               // RNE to bf16
    wf[idx] = (unsigned short)(u >> 16);

    if (blockIdx.x == 0) {
        if (threadIdx.x < NEXP) out[OFF_USE + threadIdx.x] = 0.0f;
        if (threadIdx.x == NEXP) out[OFF_TOT] = (float)((size_t)NTOK * TOPK);
    }
}

__global__ __launch_bounds__(BLK, 4) void gate_kernel(const float* __restrict__ x,
                                                      const unsigned short* __restrict__ wf,
                                                      const float* __restrict__ bias,
                                                      float* __restrict__ out) {
    // Per-wave private slices: 2x4KB x-stage dbuf; scores [16][65] f32 alias after.
    // No cross-wave sharing in the K-loop -> no barriers, counted vmcnt only.
    __shared__ __align__(16) char smem[8 * SLICE];
    __shared__ float hist[NEXP];

    const int tid  = threadIdx.x;
    const int w    = tid >> 6;
    const int lane = tid & 63;
    const int fq   = lane >> 4;   // 0..3
    const int fr   = lane & 15;   // 0..15
    const size_t rowBase = (size_t)blockIdx.x * ROWS;

    if (tid < NEXP) hist[tid] = 0.0f;

    char* myslice = smem + w * SLICE;

    // Staging: slab = 16 rows x 256 B (one 4KB buffer), 4 instrs x 1KB.
    // Instr i, lane l: slot flat = i*64+l; row = flat>>4 (0..15), phys 16B-unit
    // p = flat&15. LDS gets linear slots; SOURCE pre-swizzled: u = p ^ row, so
    // LDS[row][p] = x[row][slab*64 + (p^row)*4 ..]. Per instr the 4 rows are
    // still covered by whole 256B chunks (XOR only permutes units within the
    // chunk) -> DRAM sees sequential 256B-granule streams per row.
    const char* xb = (const char*)(x + (rowBase + (size_t)w * WROWS) * DIM);
    const char* src[4];
#pragma unroll
    for (int i = 0; i < 4; i++) {
        int flat = i * 64 + lane;
        int row = flat >> 4;
        int u = (flat & 15) ^ row;
        src[i] = xb + (size_t)row * (DIM * 4) + u * 16;
    }

#define STAGE(BUF, slab)                                                          \
    do {                                                                          \
        _Pragma("unroll")                                                         \
        for (int i_ = 0; i_ < 4; i_++)                                            \
            __builtin_amdgcn_global_load_lds(                                     \
                (const __attribute__((address_space(1))) unsigned int*)(src[i_] + (slab) * 256), \
                (__attribute__((address_space(3))) unsigned int*)(myslice + (BUF) * 4096 + i_ * 1024), \
                16, 0, 0);                                                        \
    } while (0)

    // A-fragment ds_read slot indices (16B units within a 4KB buffer):
    // K-step kk (0,1), half h: logical unit u = kk*8 + fq*2 + h, slot = fr*16 + (u^fr)
    int aslot[2][2];
#pragma unroll
    for (int kk = 0; kk < 2; kk++)
#pragma unroll
        for (int h = 0; h < 2; h++)
            aslot[kk][h] = fr * 16 + (((kk * 8 + fq * 2 + h) ^ fr) & 15);

    const bf16x8* wfv = (const bf16x8*)wf;

    f32x4 acc[4] = {};     // [nt], 16 rows x 64 experts
    bf16x8 bcur[8];        // [kk*4+nt] for current slab

    // prologue: 12 outstanding vmem (8 bfrag + 4 stage)
#pragma unroll
    for (int f = 0; f < 8; f++) bcur[f] = wfv[(size_t)f * 64 + lane];
    STAGE(0, 0);

#define GSLAB(slab, BUF, PREF)                                                    \
    {                                                                             \
        bf16x8 bnext[8];                                                          \
        if (PREF) {                                                               \
            _Pragma("unroll")                                                     \
            for (int f = 0; f < 8; f++)                                           \
                bnext[f] = wfv[(size_t)(((slab) + 1) * 8 + f) * 64 + lane];       \
            STAGE((BUF) ^ 1, (slab) + 1);                                         \
            asm volatile("s_waitcnt vmcnt(12)" ::: "memory");                     \
        } else {                                                                  \
            asm volatile("s_waitcnt vmcnt(0)" ::: "memory");                      \
        }                                                                         \
        __builtin_amdgcn_sched_barrier(0);                                        \
        const float4* xt = (const float4*)(myslice + (BUF) * 4096);               \
        _Pragma("unroll")                                                         \
        for (int kk = 0; kk < 2; kk++) {                                          \
            bf16x8 af = pack_bf16(xt[aslot[kk][0]], xt[aslot[kk][1]]);            \
            _Pragma("unroll")                                                     \
            for (int nt = 0; nt < 4; nt++)                                        \
                acc[nt] = __builtin_amdgcn_mfma_f32_16x16x32_bf16(af, bcur[kk * 4 + nt], acc[nt], 0, 0, 0); \
        }                                                                         \
        if (PREF) {                                                               \
            _Pragma("unroll")                                                     \
            for (int f = 0; f < 8; f++) bcur[f] = bnext[f];                       \
        }                                                                         \
    }

    for (int s = 0; s < NSLAB - 1; ++s) {
        GSLAB(s, s & 1, 1);
    }
    GSLAB(NSLAB - 1, (NSLAB - 1) & 1, 0);

    // scores (+bias) -> own slice, [16 rows][65] f32 (aliases stage bufs; own
    // DMA all landed via final vmcnt(0)).  C/D: col=fr, row=fq*4+r.
    float* sw = (float*)myslice;
    float bv[4];
#pragma unroll
    for (int nt = 0; nt < 4; nt++) bv[nt] = bias[nt * 16 + fr];
#pragma unroll
    for (int nt = 0; nt < 4; nt++) {
        int n = nt * 16 + fr;
#pragma unroll
        for (int r = 0; r < 4; r++)
            sw[(fq * 4 + r) * 65 + n] = acc[nt][r] + bv[nt];
    }
    __syncthreads();   // the only block-wide barrier

    // epilogue: one thread per row (threads 0..127)
    if (tid < ROWS) {
        const float* rp = (const float*)(smem + (tid >> 4) * SLICE) + (tid & 15) * 65;
        float m = rp[0];
#pragma unroll 8
        for (int e = 1; e < NEXP; e++) m = fmaxf(m, rp[e]);

        float tv[8]; int ti[8];
#pragma unroll
        for (int k = 0; k < 8; k++) { tv[k] = -1.0f; ti[k] = 0; }
        float sum = 0.0f;

#pragma unroll 4
        for (int e = 0; e < NEXP; e++) {
            float ev = __expf(rp[e] - m);   // unnormalized; same order as probs
            sum += ev;
#pragma unroll
            for (int k = 7; k >= 1; k--) {
                bool up   = ev > tv[k - 1];
                bool here = ev > tv[k];
                float nv = up ? tv[k - 1] : (here ? ev : tv[k]);
                int   ni = up ? ti[k - 1] : (here ? e : ti[k]);
                tv[k] = nv; ti[k] = ni;
            }
            bool c0 = ev > tv[0];
            ti[0] = c0 ? e : ti[0];
            tv[0] = c0 ? ev : tv[0];
        }
        float rinv = 1.0f / sum;

        size_t ro = (rowBase + tid) * TOPK;
        *(float4*)(out + ro)     = make_float4(tv[0] * rinv, tv[1] * rinv, tv[2] * rinv, tv[3] * rinv);
        *(float4*)(out + ro + 4) = make_float4(tv[4] * rinv, tv[5] * rinv, tv[6] * rinv, tv[7] * rinv);
        *(float4*)(out + OFF_IDX + ro)     = make_float4((float)ti[0], (float)ti[1], (float)ti[2], (float)ti[3]);
        *(float4*)(out + OFF_IDX + ro + 4) = make_float4((float)ti[4], (float)ti[5], (float)ti[6], (float)ti[7]);
#pragma unroll
        for (int k = 0; k < 8; k++) atomicAdd(&hist[ti[k]], 1.0f);
    }
    __syncthreads();
    if (tid < NEXP) atomicAdd(&out[OFF_USE + tid], hist[tid]);
}

extern "C" void kernel_launch(void* const* d_in, const int* in_sizes, int n_in,
                              void* d_out, int out_size, void* d_ws, size_t ws_size,
                              hipStream_t stream) {
    const float* x    = (const float*)d_in[0];
    const float* W    = (const float*)d_in[1];
    const float* bias = (const float*)d_in[2];
    float* out = (float*)d_out;
    unsigned short* wf = (unsigned short*)d_ws;   // 128 KB fragment-ordered bf16 W

    gate_prep_kernel<<<256, 256, 0, stream>>>(W, wf, out);
    gate_kernel<<<NTOK / ROWS, BLK, 0, stream>>>(x, wf, bias, out);
}

// Round 6
// 260.168 us; speedup vs baseline: 1.0066x; 1.0066x over previous
//
#include <hip/hip_runtime.h>
#include <math.h>

#define NTOK   262144
#define DIM    1024
#define NEXP   64
#define TOPK   8
#define WROWS  64           // rows per wave (4 m-tiles)
#define ROWS   256          // rows per block = 4 waves x 64 rows
#define BLK    256
#define BK     32           // K-chunk (floats) = 128 B per row
#define NKC    (DIM / BK)   // 32 K-steps
#define SLICE  16896        // per-wave LDS: 2x8KB stage dbuf | scores [64][65] f32 alias

#define OFF_IDX ((size_t)NTOK * TOPK)
#define OFF_USE (2 * (size_t)NTOK * TOPK)
#define OFF_TOT (OFF_USE + NEXP)

typedef __attribute__((ext_vector_type(8))) short bf16x8;
typedef __attribute__((ext_vector_type(4))) float f32x4;

union FragU { bf16x8 v; unsigned int u[4]; };

// pack 8 f32 (a=k0..3, b=k4..7) -> bf16x8 fragment (truncate)
__device__ __forceinline__ bf16x8 pack_bf16(float4 a, float4 b) {
    FragU r;
    r.u[0] = (__float_as_uint(a.x) >> 16) | (__float_as_uint(a.y) & 0xFFFF0000u);
    r.u[1] = (__float_as_uint(a.z) >> 16) | (__float_as_uint(a.w) & 0xFFFF0000u);
    r.u[2] = (__float_as_uint(b.x) >> 16) | (__float_as_uint(b.y) & 0xFFFF0000u);
    r.u[3] = (__float_as_uint(b.z) >> 16) | (__float_as_uint(b.w) & 0xFFFF0000u);
    return r.v;
}

// W [64][1024] f32 -> bf16 MFMA B-fragments in d_ws:
//   wf[((kc*4+nt)*64 + lane)*8 + j] = bf16(W[nt*16+(lane&15)][kc*32+(lane>>4)*8+j])
// Also init usage counters + total_tokens.
__global__ __launch_bounds__(256) void gate_prep_kernel(const float* __restrict__ W,
                                                        unsigned short* __restrict__ wf,
                                                        float* __restrict__ out) {
    int idx = blockIdx.x * 256 + threadIdx.x;      // 65536 total
    int j    = idx & 7;
    int lane = (idx >> 3) & 63;
    int nt   = (idx >> 9) & 3;
    int kc   = idx >> 11;
    int fq = lane >> 4, fr = lane & 15;
    float v = W[(size_t)(nt * 16 + fr) * DIM + kc * BK + fq * 8 + j];
    unsigned int u = __float_as_uint(v);
    u += 0x7FFFu + ((u >> 16) & 1u);               // RNE to bf16
    wf[idx] = (unsigned short)(u >> 16);

    if (blockIdx.x == 0) {
        if (threadIdx.x < NEXP) out[OFF_USE + threadIdx.x] = 0.0f;
        if (threadIdx.x == NEXP) out[OFF_TOT] = (float)((size_t)NTOK * TOPK);
    }
}

__global__ __launch_bounds__(BLK, 2) void gate_kernel(const float* __restrict__ x,
                                                      const unsigned short* __restrict__ wf,
                                                      const float* __restrict__ bias,
                                                      float* __restrict__ out) {
    // Per-wave private slices -> NO barriers in the K-loop, counted vmcnt only.
    __shared__ __align__(16) char smem[4 * SLICE];
    __shared__ float hist[NEXP];

    const int tid  = threadIdx.x;
    const int w    = tid >> 6;
    const int lane = tid & 63;
    const int fq   = lane >> 4;   // 0..3
    const int fr   = lane & 15;   // 0..15
    const size_t rowBase = (size_t)blockIdx.x * ROWS;

    if (tid < NEXP) hist[tid] = 0.0f;

    char* myslice = smem + w * SLICE;

    // Staging: 64 rows x 128 B per buffer (8 KB), 8 instrs x 1 KB.
    // Instr i, lane l: flat = i*64+l; row = flat>>3 (0..63), phys 16B-unit
    // p = flat&7; SOURCE pre-swizzled (u = p ^ (row&7)) so linear LDS dest
    // yields the swizzled layout (rule: both-sides-or-neither).
    const char* xb = (const char*)(x + (rowBase + (size_t)w * WROWS) * DIM);
    const char* src[8];
#pragma unroll
    for (int i = 0; i < 8; i++) {
        int flat = i * 64 + lane;
        int row = flat >> 3;
        int u = (flat & 7) ^ (row & 7);
        src[i] = xb + (size_t)row * (DIM * 4) + u * 16;
    }

#define STAGE(BUF, kc)                                                            \
    do {                                                                          \
        _Pragma("unroll")                                                         \
        for (int i_ = 0; i_ < 8; i_++)                                            \
            __builtin_amdgcn_global_load_lds(                                     \
                (const __attribute__((address_space(1))) unsigned int*)(src[i_] + (kc) * 128), \
                (__attribute__((address_space(3))) unsigned int*)(myslice + (BUF) * 8192 + i_ * 1024), \
                16, 0, 0);                                                        \
    } while (0)

    // A-fragment ds_read slot indices (16B units in an 8KB buffer):
    // m-tile mt, half h: row = mt*16+fr, unit = (fq*2+h) ^ (fr&7)
    int aslot[4][2];
#pragma unroll
    for (int mt = 0; mt < 4; mt++)
#pragma unroll
        for (int h = 0; h < 2; h++)
            aslot[mt][h] = (mt * 16 + fr) * 8 + (((fq * 2 + h) ^ fr) & 7);

    const bf16x8* wfv = (const bf16x8*)wf;

    f32x4 acc[4][4] = {};   // [mt][nt]
    bf16x8 bcur[4];

    // prologue: 12 outstanding vmem (4 bfrag + 8 stage)
#pragma unroll
    for (int nt = 0; nt < 4; nt++) bcur[nt] = wfv[(size_t)nt * 64 + lane];
    STAGE(0, 0);

#define GSTEP(kc, BUF, PREF)                                                      \
    {                                                                             \
        bf16x8 bnext[4];                                                          \
        if (PREF) {                                                               \
            _Pragma("unroll")                                                     \
            for (int nt = 0; nt < 4; nt++)                                        \
                bnext[nt] = wfv[(size_t)(((kc) + 1) * 4 + nt) * 64 + lane];       \
            STAGE((BUF) ^ 1, (kc) + 1);                                           \
            asm volatile("s_waitcnt vmcnt(12)" ::: "memory");                     \
        } else {                                                                  \
            asm volatile("s_waitcnt vmcnt(0)" ::: "memory");                      \
        }                                                                         \
        __builtin_amdgcn_sched_barrier(0);                                        \
        const float4* xt = (const float4*)(myslice + (BUF) * 8192);               \
        _Pragma("unroll")                                                         \
        for (int mt = 0; mt < 4; mt++) {                                          \
            bf16x8 af = pack_bf16(xt[aslot[mt][0]], xt[aslot[mt][1]]);            \
            _Pragma("unroll")                                                     \
            for (int nt = 0; nt < 4; nt++)                                        \
                acc[mt][nt] = __builtin_amdgcn_mfma_f32_16x16x32_bf16(af, bcur[nt], acc[mt][nt], 0, 0, 0); \
        }                                                                         \
        if (PREF) {                                                               \
            _Pragma("unroll")                                                     \
            for (int nt = 0; nt < 4; nt++) bcur[nt] = bnext[nt];                  \
        }                                                                         \
    }

    for (int kc = 0; kc < NKC - 2; kc += 2) {
        GSTEP(kc, 0, 1);
        GSTEP(kc + 1, 1, 1);
    }
    GSTEP(NKC - 2, 0, 1);
    GSTEP(NKC - 1, 1, 0);

    // scores (+bias) -> own slice, [64 rows][65] f32 (aliases own stage bufs;
    // own DMA done via final vmcnt(0); no cross-wave use until the barrier).
    // C/D layout: col = fr, row = fq*4 + r.
    float* sw = (float*)myslice;
    float bv[4];
#pragma unroll
    for (int nt = 0; nt < 4; nt++) bv[nt] = bias[nt * 16 + fr];
#pragma unroll
    for (int mt = 0; mt < 4; mt++) {
        int mbase = mt * 16 + fq * 4;
#pragma unroll
        for (int nt = 0; nt < 4; nt++) {
            int n = nt * 16 + fr;
#pragma unroll
            for (int r = 0; r < 4; r++)
                sw[(mbase + r) * 65 + n] = acc[mt][nt][r] + bv[nt];
        }
    }
    __syncthreads();   // the only block-wide barrier

    // epilogue: one thread per row (all 256 threads)
    {
        const float* rp = (const float*)(smem + (tid >> 6) * SLICE) + (tid & 63) * 65;

        // top-8 selection on RAW scores (exp is monotone; strict > keeps
        // ascending index order among ties, matching lax.top_k), plus max.
        float tv[8]; int ti[8];
#pragma unroll
        for (int k = 0; k < 8; k++) { tv[k] = -1e30f; ti[k] = 0; }

#pragma unroll 4
        for (int e = 0; e < NEXP; e++) {
            float s = rp[e];
#pragma unroll
            for (int k = 7; k >= 1; k--) {
                bool up   = s > tv[k - 1];
                bool here = s > tv[k];
                float nv = up ? tv[k - 1] : (here ? s : tv[k]);
                int   ni = up ? ti[k - 1] : (here ? e : ti[k]);
                tv[k] = nv; ti[k] = ni;
            }
            bool c0 = s > tv[0];
            ti[0] = c0 ? e : ti[0];
            tv[0] = c0 ? s : tv[0];
        }
        float m = tv[0];   // row max

        float sum = 0.0f;
#pragma unroll 8
        for (int e = 0; e < NEXP; e++) sum += __expf(rp[e] - m);
        float rinv = 1.0f / sum;

        float wv_[8];
#pragma unroll
        for (int k = 0; k < 8; k++) wv_[k] = __expf(tv[k] - m) * rinv;

        size_t ro = (rowBase + tid) * TOPK;
        *(float4*)(out + ro)     = make_float4(wv_[0], wv_[1], wv_[2], wv_[3]);
        *(float4*)(out + ro + 4) = make_float4(wv_[4], wv_[5], wv_[6], wv_[7]);
        *(float4*)(out + OFF_IDX + ro)     = make_float4((float)ti[0], (float)ti[1], (float)ti[2], (float)ti[3]);
        *(float4*)(out + OFF_IDX + ro + 4) = make_float4((float)ti[4], (float)ti[5], (float)ti[6], (float)ti[7]);
#pragma unroll
        for (int k = 0; k < 8; k++) atomicAdd(&hist[ti[k]], 1.0f);
    }
    __syncthreads();
    if (tid < NEXP) atomicAdd(&out[OFF_USE + tid], hist[tid]);
}

extern "C" void kernel_launch(void* const* d_in, const int* in_sizes, int n_in,
                              void* d_out, int out_size, void* d_ws, size_t ws_size,
                              hipStream_t stream) {
    const float* x    = (const float*)d_in[0];
    const float* W    = (const float*)d_in[1];
    const float* bias = (const float*)d_in[2];
    float* out = (float*)d_out;
    unsigned short* wf = (unsigned short*)d_ws;   // 128 KB fragment-ordered bf16 W

    gate_prep_kernel<<<256, 256, 0, stream>>>(W, wf, out);
    gate_kernel<<<NTOK / ROWS, BLK, 0, stream>>>(x, wf, bias, out);
}

// Round 7
// 254.491 us; speedup vs baseline: 1.0290x; 1.0223x over previous
//
#include <hip/hip_runtime.h>
#include <math.h>

#define NTOK   262144
#define DIM    1024
#define NEXP   64
#define TOPK   8
#define WROWS  32           // rows per wave (2 m-tiles)
#define ROWS   128          // rows per block = 4 waves x 32 rows
#define BLK    256
#define BK     32           // K-chunk (floats) = 128 B per row
#define NKC    (DIM / BK)   // 32 K-steps
#define BUFSZ  4096         // 32 rows x 128 B
#define SLICE  (3 * BUFSZ)  // per-wave: TRIPLE-buffered stage; scores [32][65] alias

#define OFF_IDX ((size_t)NTOK * TOPK)
#define OFF_USE (2 * (size_t)NTOK * TOPK)
#define OFF_TOT (OFF_USE + NEXP)

typedef __attribute__((ext_vector_type(8))) short bf16x8;
typedef __attribute__((ext_vector_type(4))) float f32x4;

union FragU { bf16x8 v; unsigned int u[4]; };

// pack 8 f32 (a=k0..3, b=k4..7) -> bf16x8 fragment (truncate)
__device__ __forceinline__ bf16x8 pack_bf16(float4 a, float4 b) {
    FragU r;
    r.u[0] = (__float_as_uint(a.x) >> 16) | (__float_as_uint(a.y) & 0xFFFF0000u);
    r.u[1] = (__float_as_uint(a.z) >> 16) | (__float_as_uint(a.w) & 0xFFFF0000u);
    r.u[2] = (__float_as_uint(b.x) >> 16) | (__float_as_uint(b.y) & 0xFFFF0000u);
    r.u[3] = (__float_as_uint(b.z) >> 16) | (__float_as_uint(b.w) & 0xFFFF0000u);
    return r.v;
}

// W [64][1024] f32 -> bf16 MFMA B-fragments in d_ws:
//   wf[((kc*4+nt)*64 + lane)*8 + j] = bf16(W[nt*16+(lane&15)][kc*32+(lane>>4)*8+j])
// Also init usage counters + total_tokens.
__global__ __launch_bounds__(256) void gate_prep_kernel(const float* __restrict__ W,
                                                        unsigned short* __restrict__ wf,
                                                        float* __restrict__ out) {
    int idx = blockIdx.x * 256 + threadIdx.x;      // 65536 total
    int j    = idx & 7;
    int lane = (idx >> 3) & 63;
    int nt   = (idx >> 9) & 3;
    int kc   = idx >> 11;
    int fq = lane >> 4, fr = lane & 15;
    float v = W[(size_t)(nt * 16 + fr) * DIM + kc * BK + fq * 8 + j];
    unsigned int u = __float_as_uint(v);
    u += 0x7FFFu + ((u >> 16) & 1u);               // RNE to bf16
    wf[idx] = (unsigned short)(u >> 16);

    if (blockIdx.x == 0) {
        if (threadIdx.x < NEXP) out[OFF_USE + threadIdx.x] = 0.0f;
        if (threadIdx.x == NEXP) out[OFF_TOT] = (float)((size_t)NTOK * TOPK);
    }
}

__global__ __launch_bounds__(BLK, 3) void gate_kernel(const float* __restrict__ x,
                                                      const unsigned short* __restrict__ wf,
                                                      const float* __restrict__ bias,
                                                      float* __restrict__ out) {
    // Per-wave private slices -> NO barriers in the K-loop, counted vmcnt only.
    // Depth-2 stage pipeline: at step k we wait for stage(k) issued at step k-2.
    __shared__ __align__(16) char smem[4 * SLICE];
    __shared__ float hist[NEXP];

    const int tid  = threadIdx.x;
    const int w    = tid >> 6;
    const int lane = tid & 63;
    const int fq   = lane >> 4;   // 0..3
    const int fr   = lane & 15;   // 0..15
    const size_t rowBase = (size_t)blockIdx.x * ROWS;

    if (tid < NEXP) hist[tid] = 0.0f;

    char* myslice = smem + w * SLICE;

    // Staging: 32 rows x 128 B per buffer (4 KB), 4 instrs x 1 KB.
    // Instr i, lane l: flat = i*64+l; row = flat>>3 (0..31), phys 16B-unit
    // p = flat&7; SOURCE pre-swizzled (u = p ^ (row&7)) so the linear LDS
    // dest yields the swizzled layout (both-sides-or-neither rule).
    const char* xb = (const char*)(x + (rowBase + (size_t)w * WROWS) * DIM);
    const char* src[4];
#pragma unroll
    for (int i = 0; i < 4; i++) {
        int flat = i * 64 + lane;
        int row = flat >> 3;
        int u = (flat & 7) ^ (row & 7);
        src[i] = xb + (size_t)row * (DIM * 4) + u * 16;
    }

#define STAGE(BUF, kc)                                                            \
    do {                                                                          \
        _Pragma("unroll")                                                         \
        for (int i_ = 0; i_ < 4; i_++)                                            \
            __builtin_amdgcn_global_load_lds(                                     \
                (const __attribute__((address_space(1))) unsigned int*)(src[i_] + (kc) * 128), \
                (__attribute__((address_space(3))) unsigned int*)(myslice + (BUF) * BUFSZ + i_ * 1024), \
                16, 0, 0);                                                        \
    } while (0)

    // A-fragment ds_read slot indices (16B units within a 4KB buffer):
    // m-tile mt, half h: row = mt*16+fr, unit = (fq*2+h) ^ (fr&7)
    int aslot[2][2];
#pragma unroll
    for (int mt = 0; mt < 2; mt++)
#pragma unroll
        for (int h = 0; h < 2; h++)
            aslot[mt][h] = (mt * 16 + fr) * 8 + (((fq * 2 + h) ^ fr) & 7);

    const bf16x8* wfv = (const bf16x8*)wf;

    f32x4 acc[2][4] = {};   // [mt][nt]
    bf16x8 bcur[4];

    // Prologue FIFO: bfrag(0) [4] | stage(0) [4] | stage(1) [4]  -> 12 outstanding
#pragma unroll
    for (int nt = 0; nt < 4; nt++) bcur[nt] = wfv[(size_t)nt * 64 + lane];
    __builtin_amdgcn_sched_barrier(0);
    STAGE(0, 0);
    STAGE(1, 1);

    // Step k: issue bfrag(k+1) FIRST (fast L2), then stage(k+2); then wait
    // vmcnt(12) -> completes exactly [bfrag(k), stage(k)] (stage issued at
    // step k-2: depth 2). Never drains to 0 in-loop.
#define GSTEP(kc, BUF, SBUF, MODE)                                                \
    {                                                                             \
        bf16x8 bnext[4];                                                          \
        if ((MODE) >= 1) {                                                        \
            _Pragma("unroll")                                                     \
            for (int nt = 0; nt < 4; nt++)                                        \
                bnext[nt] = wfv[(size_t)(((kc) + 1) * 4 + nt) * 64 + lane];       \
            __builtin_amdgcn_sched_barrier(0);                                    \
        }                                                                         \
        if ((MODE) == 2) STAGE(SBUF, (kc) + 2);                                   \
        if ((MODE) == 2)      asm volatile("s_waitcnt vmcnt(12)" ::: "memory");   \
        else if ((MODE) == 1) asm volatile("s_waitcnt vmcnt(8)" ::: "memory");    \
        else                  asm volatile("s_waitcnt vmcnt(0)" ::: "memory");    \
        __builtin_amdgcn_sched_barrier(0);                                        \
        const float4* xt = (const float4*)(myslice + (BUF) * BUFSZ);              \
        _Pragma("unroll")                                                         \
        for (int mt = 0; mt < 2; mt++) {                                          \
            bf16x8 af = pack_bf16(xt[aslot[mt][0]], xt[aslot[mt][1]]);            \
            _Pragma("unroll")                                                     \
            for (int nt = 0; nt < 4; nt++)                                        \
                acc[mt][nt] = __builtin_amdgcn_mfma_f32_16x16x32_bf16(af, bcur[nt], acc[mt][nt], 0, 0, 0); \
        }                                                                         \
        if ((MODE) >= 1) {                                                        \
            _Pragma("unroll")                                                     \
            for (int nt = 0; nt < 4; nt++) bcur[nt] = bnext[nt];                  \
        }                                                                         \
    }

#pragma unroll 1
    for (int t = 0; t < 10; t++) {            // k = 0..29, buf = k%3
        GSTEP(3 * t,     0, 2, 2);
        GSTEP(3 * t + 1, 1, 0, 2);
        GSTEP(3 * t + 2, 2, 1, 2);
    }
    GSTEP(30, 0, 0, 1);                       // waits [bfrag(30), stage(30)]
    GSTEP(31, 1, 0, 0);                       // drains

    // scores (+bias) -> own slice, [32 rows][65] f32 (aliases own stage bufs;
    // own DMA done via final vmcnt(0)).  C/D layout: col = fr, row = fq*4 + r.
    float* sw = (float*)myslice;
    float bv[4];
#pragma unroll
    for (int nt = 0; nt < 4; nt++) bv[nt] = bias[nt * 16 + fr];
#pragma unroll
    for (int mt = 0; mt < 2; mt++) {
        int mbase = mt * 16 + fq * 4;
#pragma unroll
        for (int nt = 0; nt < 4; nt++) {
            int n = nt * 16 + fr;
#pragma unroll
            for (int r = 0; r < 4; r++)
                sw[(mbase + r) * 65 + n] = acc[mt][nt][r] + bv[nt];
        }
    }
    __syncthreads();   // the only block-wide barrier

    // epilogue: one thread per row (threads 0..127)
    if (tid < ROWS) {
        const float* rp = (const float*)(smem + (tid >> 5) * SLICE) + (tid & 31) * 65;

        // top-8 on RAW scores (exp monotone; strict > keeps ascending index
        // order among ties, matching lax.top_k)
        float tv[8]; int ti[8];
#pragma unroll
        for (int k = 0; k < 8; k++) { tv[k] = -1e30f; ti[k] = 0; }

#pragma unroll 4
        for (int e = 0; e < NEXP; e++) {
            float s = rp[e];
#pragma unroll
            for (int k = 7; k >= 1; k--) {
                bool up   = s > tv[k - 1];
                bool here = s > tv[k];
                float nv = up ? tv[k - 1] : (here ? s : tv[k]);
                int   ni = up ? ti[k - 1] : (here ? e : ti[k]);
                tv[k] = nv; ti[k] = ni;
            }
            bool c0 = s > tv[0];
            ti[0] = c0 ? e : ti[0];
            tv[0] = c0 ? s : tv[0];
        }
        float m = tv[0];   // row max

        float sum = 0.0f;
#pragma unroll 8
        for (int e = 0; e < NEXP; e++) sum += __expf(rp[e] - m);
        float rinv = 1.0f / sum;

        float wv_[8];
#pragma unroll
        for (int k = 0; k < 8; k++) wv_[k] = __expf(tv[k] - m) * rinv;

        size_t ro = (rowBase + tid) * TOPK;
        *(float4*)(out + ro)     = make_float4(wv_[0], wv_[1], wv_[2], wv_[3]);
        *(float4*)(out + ro + 4) = make_float4(wv_[4], wv_[5], wv_[6], wv_[7]);
        *(float4*)(out + OFF_IDX + ro)     = make_float4((float)ti[0], (float)ti[1], (float)ti[2], (float)ti[3]);
        *(float4*)(out + OFF_IDX + ro + 4) = make_float4((float)ti[4], (float)ti[5], (float)ti[6], (float)ti[7]);
#pragma unroll
        for (int k = 0; k < 8; k++) atomicAdd(&hist[ti[k]], 1.0f);
    }
    __syncthreads();
    if (tid < NEXP) atomicAdd(&out[OFF_USE + tid], hist[tid]);
}

extern "C" void kernel_launch(void* const* d_in, const int* in_sizes, int n_in,
                              void* d_out, int out_size, void* d_ws, size_t ws_size,
                              hipStream_t stream) {
    const float* x    = (const float*)d_in[0];
    const float* W    = (const float*)d_in[1];
    const float* bias = (const float*)d_in[2];
    float* out = (float*)d_out;
    unsigned short* wf = (unsigned short*)d_ws;   // 128 KB fragment-ordered bf16 W

    gate_prep_kernel<<<256, 256, 0, stream>>>(W, wf, out);
    gate_kernel<<<NTOK / ROWS, BLK, 0, stream>>>(x, wf, bias, out);
}

// Round 8
// 245.319 us; speedup vs baseline: 1.0675x; 1.0374x over previous
//
#include <hip/hip_runtime.h>
#include <math.h>

#define NTOK   262144
#define DIM    1024
#define NEXP   64
#define TOPK   8
#define WROWS  32           // rows per wave (2 m-tiles)
#define ROWS   128          // rows per block = 4 waves x 32 rows
#define BLK    256
#define BK     32           // K-chunk (floats) = 128 B per row
#define NKC    (DIM / BK)   // 32 K-steps
#define BUFSZ  4096         // 32 rows x 128 B
#define SLICE  (3 * BUFSZ)  // per-wave: TRIPLE-buffered stage; scores [32][65] alias

#define OFF_IDX ((size_t)NTOK * TOPK)
#define OFF_USE (2 * (size_t)NTOK * TOPK)
#define OFF_TOT (OFF_USE + NEXP)

typedef __attribute__((ext_vector_type(8))) short bf16x8;
typedef __attribute__((ext_vector_type(4))) float f32x4;

union FragU { bf16x8 v; unsigned int u[4]; };

// pack 8 f32 (a=k0..3, b=k4..7) -> bf16x8 fragment (truncate)
__device__ __forceinline__ bf16x8 pack_bf16(float4 a, float4 b) {
    FragU r;
    r.u[0] = (__float_as_uint(a.x) >> 16) | (__float_as_uint(a.y) & 0xFFFF0000u);
    r.u[1] = (__float_as_uint(a.z) >> 16) | (__float_as_uint(a.w) & 0xFFFF0000u);
    r.u[2] = (__float_as_uint(b.x) >> 16) | (__float_as_uint(b.y) & 0xFFFF0000u);
    r.u[3] = (__float_as_uint(b.z) >> 16) | (__float_as_uint(b.w) & 0xFFFF0000u);
    return r.v;
}

// W [64][1024] f32 -> bf16 MFMA B-fragments in d_ws:
//   wf[((kc*4+nt)*64 + lane)*8 + j] = bf16(W[nt*16+(lane&15)][kc*32+(lane>>4)*8+j])
// Also init usage counters + total_tokens.
__global__ __launch_bounds__(256) void gate_prep_kernel(const float* __restrict__ W,
                                                        unsigned short* __restrict__ wf,
                                                        float* __restrict__ out) {
    int idx = blockIdx.x * 256 + threadIdx.x;      // 65536 total
    int j    = idx & 7;
    int lane = (idx >> 3) & 63;
    int nt   = (idx >> 9) & 3;
    int kc   = idx >> 11;
    int fq = lane >> 4, fr = lane & 15;
    float v = W[(size_t)(nt * 16 + fr) * DIM + kc * BK + fq * 8 + j];
    unsigned int u = __float_as_uint(v);
    u += 0x7FFFu + ((u >> 16) & 1u);               // RNE to bf16
    wf[idx] = (unsigned short)(u >> 16);

    if (blockIdx.x == 0) {
        if (threadIdx.x < NEXP) out[OFF_USE + threadIdx.x] = 0.0f;
        if (threadIdx.x == NEXP) out[OFF_TOT] = (float)((size_t)NTOK * TOPK);
    }
}

__global__ __launch_bounds__(BLK, 3) void gate_kernel(const float* __restrict__ x,
                                                      const unsigned short* __restrict__ wf,
                                                      const float* __restrict__ bias,
                                                      float* __restrict__ out) {
    // Per-wave private slices -> NO barriers in the K-loop, counted vmcnt only.
    // Depth-2 stage pipeline; staging loads marked NT (CPol bit1) so the pure
    // streaming x read does not allocate/thrash L1/L2.
    __shared__ __align__(16) char smem[4 * SLICE];
    __shared__ float hist[NEXP];

    const int tid  = threadIdx.x;
    const int w    = tid >> 6;
    const int lane = tid & 63;
    const int fq   = lane >> 4;   // 0..3
    const int fr   = lane & 15;   // 0..15
    const size_t rowBase = (size_t)blockIdx.x * ROWS;

    if (tid < NEXP) hist[tid] = 0.0f;

    char* myslice = smem + w * SLICE;

    // Staging: 32 rows x 128 B per buffer (4 KB), 4 instrs x 1 KB.
    // Instr i, lane l: flat = i*64+l; row = flat>>3 (0..31), phys 16B-unit
    // p = flat&7; SOURCE pre-swizzled (u = p ^ (row&7)) so the linear LDS
    // dest yields the swizzled layout (both-sides-or-neither rule).
    const char* xb = (const char*)(x + (rowBase + (size_t)w * WROWS) * DIM);
    const char* src[4];
#pragma unroll
    for (int i = 0; i < 4; i++) {
        int flat = i * 64 + lane;
        int row = flat >> 3;
        int u = (flat & 7) ^ (row & 7);
        src[i] = xb + (size_t)row * (DIM * 4) + u * 16;
    }

#define STAGE(BUF, kc)                                                            \
    do {                                                                          \
        _Pragma("unroll")                                                         \
        for (int i_ = 0; i_ < 4; i_++)                                            \
            __builtin_amdgcn_global_load_lds(                                     \
                (const __attribute__((address_space(1))) unsigned int*)(src[i_] + (kc) * 128), \
                (__attribute__((address_space(3))) unsigned int*)(myslice + (BUF) * BUFSZ + i_ * 1024), \
                16, 0, 2 /* NT: non-temporal streaming read */);                  \
    } while (0)

    // A-fragment ds_read slot indices (16B units within a 4KB buffer):
    // m-tile mt, half h: row = mt*16+fr, unit = (fq*2+h) ^ (fr&7)
    int aslot[2][2];
#pragma unroll
    for (int mt = 0; mt < 2; mt++)
#pragma unroll
        for (int h = 0; h < 2; h++)
            aslot[mt][h] = (mt * 16 + fr) * 8 + (((fq * 2 + h) ^ fr) & 7);

    const bf16x8* wfv = (const bf16x8*)wf;

    f32x4 acc[2][4] = {};   // [mt][nt]
    bf16x8 bcur[4];

    // Prologue FIFO: bfrag(0) [4] | stage(0) [4] | stage(1) [4]  -> 12 outstanding
#pragma unroll
    for (int nt = 0; nt < 4; nt++) bcur[nt] = wfv[(size_t)nt * 64 + lane];
    __builtin_amdgcn_sched_barrier(0);
    STAGE(0, 0);
    STAGE(1, 1);

    // Step k: issue bfrag(k+1) FIRST (fast L2), then stage(k+2); then wait
    // vmcnt(12) -> completes exactly [bfrag(k), stage(k)] (stage issued at
    // step k-2: depth 2). Never drains to 0 in-loop.
#define GSTEP(kc, BUF, SBUF, MODE)                                                \
    {                                                                             \
        bf16x8 bnext[4];                                                          \
        if ((MODE) >= 1) {                                                        \
            _Pragma("unroll")                                                     \
            for (int nt = 0; nt < 4; nt++)                                        \
                bnext[nt] = wfv[(size_t)(((kc) + 1) * 4 + nt) * 64 + lane];       \
            __builtin_amdgcn_sched_barrier(0);                                    \
        }                                                                         \
        if ((MODE) == 2) STAGE(SBUF, (kc) + 2);                                   \
        if ((MODE) == 2)      asm volatile("s_waitcnt vmcnt(12)" ::: "memory");   \
        else if ((MODE) == 1) asm volatile("s_waitcnt vmcnt(8)" ::: "memory");    \
        else                  asm volatile("s_waitcnt vmcnt(0)" ::: "memory");    \
        __builtin_amdgcn_sched_barrier(0);                                        \
        const float4* xt = (const float4*)(myslice + (BUF) * BUFSZ);              \
        _Pragma("unroll")                                                         \
        for (int mt = 0; mt < 2; mt++) {                                          \
            bf16x8 af = pack_bf16(xt[aslot[mt][0]], xt[aslot[mt][1]]);            \
            _Pragma("unroll")                                                     \
            for (int nt = 0; nt < 4; nt++)                                        \
                acc[mt][nt] = __builtin_amdgcn_mfma_f32_16x16x32_bf16(af, bcur[nt], acc[mt][nt], 0, 0, 0); \
        }                                                                         \
        if ((MODE) >= 1) {                                                        \
            _Pragma("unroll")                                                     \
            for (int nt = 0; nt < 4; nt++) bcur[nt] = bnext[nt];                  \
        }                                                                         \
    }

#pragma unroll 1
    for (int t = 0; t < 10; t++) {            // k = 0..29, buf = k%3
        GSTEP(3 * t,     0, 2, 2);
        GSTEP(3 * t + 1, 1, 0, 2);
        GSTEP(3 * t + 2, 2, 1, 2);
    }
    GSTEP(30, 0, 0, 1);                       // waits [bfrag(30), stage(30)]
    GSTEP(31, 1, 0, 0);                       // drains

    // scores (+bias) -> own slice, [32 rows][65] f32 (aliases own stage bufs;
    // own DMA done via final vmcnt(0)).  C/D layout: col = fr, row = fq*4 + r.
    float* sw = (float*)myslice;
    float bv[4];
#pragma unroll
    for (int nt = 0; nt < 4; nt++) bv[nt] = bias[nt * 16 + fr];
#pragma unroll
    for (int mt = 0; mt < 2; mt++) {
        int mbase = mt * 16 + fq * 4;
#pragma unroll
        for (int nt = 0; nt < 4; nt++) {
            int n = nt * 16 + fr;
#pragma unroll
            for (int r = 0; r < 4; r++)
                sw[(mbase + r) * 65 + n] = acc[mt][nt][r] + bv[nt];
        }
    }
    __syncthreads();   // the only block-wide barrier

    // epilogue: one thread per row (threads 0..127)
    if (tid < ROWS) {
        const float* rp = (const float*)(smem + (tid >> 5) * SLICE) + (tid & 31) * 65;

        // top-8 on RAW scores (exp monotone; strict > keeps ascending index
        // order among ties, matching lax.top_k)
        float tv[8]; int ti[8];
#pragma unroll
        for (int k = 0; k < 8; k++) { tv[k] = -1e30f; ti[k] = 0; }

#pragma unroll 4
        for (int e = 0; e < NEXP; e++) {
            float s = rp[e];
#pragma unroll
            for (int k = 7; k >= 1; k--) {
                bool up   = s > tv[k - 1];
                bool here = s > tv[k];
                float nv = up ? tv[k - 1] : (here ? s : tv[k]);
                int   ni = up ? ti[k - 1] : (here ? e : ti[k]);
                tv[k] = nv; ti[k] = ni;
            }
            bool c0 = s > tv[0];
            ti[0] = c0 ? e : ti[0];
            tv[0] = c0 ? s : tv[0];
        }
        float m = tv[0];   // row max

        float sum = 0.0f;
#pragma unroll 8
        for (int e = 0; e < NEXP; e++) sum += __expf(rp[e] - m);
        float rinv = 1.0f / sum;

        float wv_[8];
#pragma unroll
        for (int k = 0; k < 8; k++) wv_[k] = __expf(tv[k] - m) * rinv;

        size_t ro = (rowBase + tid) * TOPK;
        *(float4*)(out + ro)     = make_float4(wv_[0], wv_[1], wv_[2], wv_[3]);
        *(float4*)(out + ro + 4) = make_float4(wv_[4], wv_[5], wv_[6], wv_[7]);
        *(float4*)(out + OFF_IDX + ro)     = make_float4((float)ti[0], (float)ti[1], (float)ti[2], (float)ti[3]);
        *(float4*)(out + OFF_IDX + ro + 4) = make_float4((float)ti[4], (float)ti[5], (float)ti[6], (float)ti[7]);
#pragma unroll
        for (int k = 0; k < 8; k++) atomicAdd(&hist[ti[k]], 1.0f);
    }
    __syncthreads();
    if (tid < NEXP) atomicAdd(&out[OFF_USE + tid], hist[tid]);
}

extern "C" void kernel_launch(void* const* d_in, const int* in_sizes, int n_in,
                              void* d_out, int out_size, void* d_ws, size_t ws_size,
                              hipStream_t stream) {
    const float* x    = (const float*)d_in[0];
    const float* W    = (const float*)d_in[1];
    const float* bias = (const float*)d_in[2];
    float* out = (float*)d_out;
    unsigned short* wf = (unsigned short*)d_ws;   // 128 KB fragment-ordered bf16 W

    gate_prep_kernel<<<256, 256, 0, stream>>>(W, wf, out);
    gate_kernel<<<NTOK / ROWS, BLK, 0, stream>>>(x, wf, bias, out);
}

// Round 9
// 222.055 us; speedup vs baseline: 1.1793x; 1.1048x over previous
//
#include <hip/hip_runtime.h>
#include <math.h>

#define NTOK   262144
#define DIM    1024
#define NEXP   64
#define TOPK   8
#define WROWS  32           // rows per wave (2 m-tiles)
#define ROWS   128          // rows per block = 4 waves x 32 rows
#define BLK    256
#define BK     32           // K-chunk (floats) = 128 B per row
#define NKC    (DIM / BK)   // 32 K-steps
#define BUFSZ  4096         // 32 rows x 128 B
#define SLICE  (3 * BUFSZ)  // per-wave: TRIPLE-buffered stage; scores [32][65] alias

#define OFF_IDX ((size_t)NTOK * TOPK)
#define OFF_USE (2 * (size_t)NTOK * TOPK)
#define OFF_TOT (OFF_USE + NEXP)

typedef __attribute__((ext_vector_type(8))) short bf16x8;
typedef __attribute__((ext_vector_type(4))) float f32x4;

union FragU { bf16x8 v; unsigned int u[4]; };

// pack 8 f32 (a=k0..3, b=k4..7) -> bf16x8 fragment (truncate)
__device__ __forceinline__ bf16x8 pack_bf16(float4 a, float4 b) {
    FragU r;
    r.u[0] = (__float_as_uint(a.x) >> 16) | (__float_as_uint(a.y) & 0xFFFF0000u);
    r.u[1] = (__float_as_uint(a.z) >> 16) | (__float_as_uint(a.w) & 0xFFFF0000u);
    r.u[2] = (__float_as_uint(b.x) >> 16) | (__float_as_uint(b.y) & 0xFFFF0000u);
    r.u[3] = (__float_as_uint(b.z) >> 16) | (__float_as_uint(b.w) & 0xFFFF0000u);
    return r.v;
}

// W [64][1024] f32 -> bf16 MFMA B-fragments in d_ws:
//   wf[((kc*4+nt)*64 + lane)*8 + j] = bf16(W[nt*16+(lane&15)][kc*32+(lane>>4)*8+j])
// Also init usage counters + total_tokens.
__global__ __launch_bounds__(256) void gate_prep_kernel(const float* __restrict__ W,
                                                        unsigned short* __restrict__ wf,
                                                        float* __restrict__ out) {
    int idx = blockIdx.x * 256 + threadIdx.x;      // 65536 total
    int j    = idx & 7;
    int lane = (idx >> 3) & 63;
    int nt   = (idx >> 9) & 3;
    int kc   = idx >> 11;
    int fq = lane >> 4, fr = lane & 15;
    float v = W[(size_t)(nt * 16 + fr) * DIM + kc * BK + fq * 8 + j];
    unsigned int u = __float_as_uint(v);
    u += 0x7FFFu + ((u >> 16) & 1u);               // RNE to bf16
    wf[idx] = (unsigned short)(u >> 16);

    if (blockIdx.x == 0) {
        if (threadIdx.x < NEXP) out[OFF_USE + threadIdx.x] = 0.0f;
        if (threadIdx.x == NEXP) out[OFF_TOT] = (float)((size_t)NTOK * TOPK);
    }
}

__global__ __launch_bounds__(BLK, 3) void gate_kernel(const float* __restrict__ x,
                                                      const unsigned short* __restrict__ wf,
                                                      const float* __restrict__ bias,
                                                      float* __restrict__ out) {
    // Per-wave private slices -> NO barriers in the K-loop, counted vmcnt only.
    // Depth-2 stage pipeline, NT staging loads, and PER-WAVE K-PHASE ROTATION:
    // wave starts its circular K-walk at kc0 = (block + 8*wave) & 31 so that
    // chip-wide, in-flight request offsets (kc*128) cover all 32 slots evenly
    // -> no HBM channel hot-spotting from lockstep strided bursts.
    __shared__ __align__(16) char smem[4 * SLICE];
    __shared__ float hist[NEXP];

    const int tid  = threadIdx.x;
    const int w    = tid >> 6;
    const int lane = tid & 63;
    const int fq   = lane >> 4;   // 0..3
    const int fr   = lane & 15;   // 0..15
    const size_t rowBase = (size_t)blockIdx.x * ROWS;

    if (tid < NEXP) hist[tid] = 0.0f;

    char* myslice = smem + w * SLICE;

    // Staging: 32 rows x 128 B per buffer (4 KB), 4 instrs x 1 KB.
    // Instr i, lane l: flat = i*64+l; row = flat>>3 (0..31), phys 16B-unit
    // p = flat&7; SOURCE pre-swizzled (u = p ^ (row&7)) so the linear LDS
    // dest yields the swizzled layout (both-sides-or-neither rule).
    const char* xb = (const char*)(x + (rowBase + (size_t)w * WROWS) * DIM);
    const char* src[4];
#pragma unroll
    for (int i = 0; i < 4; i++) {
        int flat = i * 64 + lane;
        int row = flat >> 3;
        int u = (flat & 7) ^ (row & 7);
        src[i] = xb + (size_t)row * (DIM * 4) + u * 16;
    }

#define STAGE(BUF, kc)                                                            \
    do {                                                                          \
        _Pragma("unroll")                                                         \
        for (int i_ = 0; i_ < 4; i_++)                                            \
            __builtin_amdgcn_global_load_lds(                                     \
                (const __attribute__((address_space(1))) unsigned int*)(src[i_] + (size_t)(kc) * 128), \
                (__attribute__((address_space(3))) unsigned int*)(myslice + (BUF) * BUFSZ + i_ * 1024), \
                16, 0, 2 /* NT: non-temporal streaming read */);                  \
    } while (0)

    // A-fragment ds_read slot indices (16B units within a 4KB buffer):
    // m-tile mt, half h: row = mt*16+fr, unit = (fq*2+h) ^ (fr&7)
    int aslot[2][2];
#pragma unroll
    for (int mt = 0; mt < 2; mt++)
#pragma unroll
        for (int h = 0; h < 2; h++)
            aslot[mt][h] = (mt * 16 + fr) * 8 + (((fq * 2 + h) ^ fr) & 7);

    const bf16x8* wfv = (const bf16x8*)wf;

    f32x4 acc[2][4] = {};   // [mt][nt]
    bf16x8 bcur[4];

    // K-phase rotation start
    const int kc0 = ((int)blockIdx.x + (w << 3)) & 31;

    // Prologue FIFO: bfrag(kc0) [4] | stage(kc0) [4] | stage(kc0+1) [4] -> 12 outstanding
#pragma unroll
    for (int nt = 0; nt < 4; nt++) bcur[nt] = wfv[(size_t)(kc0 * 4 + nt) * 64 + lane];
    __builtin_amdgcn_sched_barrier(0);
    STAGE(0, kc0);
    STAGE(1, (kc0 + 1) & 31);

    // Step: issue bfrag(next) FIRST (fast L2), then stage(+2); then wait
    // vmcnt(12) -> completes exactly [bfrag(cur), stage(cur)] (stage issued
    // two steps ago: depth 2). Never drains to 0 in-loop.
#define GSTEP(KC, BUF, SBUF, MODE)                                               \
    {                                                                             \
        const int kc_ = (KC);                                                     \
        bf16x8 bnext[4];                                                          \
        if ((MODE) >= 1) {                                                        \
            const int kn_ = (kc_ + 1) & 31;                                       \
            _Pragma("unroll")                                                     \
            for (int nt = 0; nt < 4; nt++)                                        \
                bnext[nt] = wfv[(size_t)(kn_ * 4 + nt) * 64 + lane];              \
            __builtin_amdgcn_sched_barrier(0);                                    \
        }                                                                         \
        if ((MODE) == 2) STAGE(SBUF, (kc_ + 2) & 31);                             \
        if ((MODE) == 2)      asm volatile("s_waitcnt vmcnt(12)" ::: "memory");   \
        else if ((MODE) == 1) asm volatile("s_waitcnt vmcnt(8)" ::: "memory");    \
        else                  asm volatile("s_waitcnt vmcnt(0)" ::: "memory");    \
        __builtin_amdgcn_sched_barrier(0);                                        \
        const float4* xt = (const float4*)(myslice + (BUF) * BUFSZ);              \
        _Pragma("unroll")                                                         \
        for (int mt = 0; mt < 2; mt++) {                                          \
            bf16x8 af = pack_bf16(xt[aslot[mt][0]], xt[aslot[mt][1]]);            \
            _Pragma("unroll")                                                     \
            for (int nt = 0; nt < 4; nt++)                                        \
                acc[mt][nt] = __builtin_amdgcn_mfma_f32_16x16x32_bf16(af, bcur[nt], acc[mt][nt], 0, 0, 0); \
        }                                                                         \
        if ((MODE) >= 1) {                                                        \
            _Pragma("unroll")                                                     \
            for (int nt = 0; nt < 4; nt++) bcur[nt] = bnext[nt];                  \
        }                                                                         \
    }

#pragma unroll 1
    for (int t = 0; t < 10; t++) {            // steps 0..29, buf = t%3
        GSTEP((kc0 + 3 * t) & 31,     0, 2, 2);
        GSTEP((kc0 + 3 * t + 1) & 31, 1, 0, 2);
        GSTEP((kc0 + 3 * t + 2) & 31, 2, 1, 2);
    }
    GSTEP((kc0 + 30) & 31, 0, 0, 1);          // waits [bfrag, stage] of step 30
    GSTEP((kc0 + 31) & 31, 1, 0, 0);          // drains

    // scores (+bias) -> own slice, [32 rows][65] f32 (aliases own stage bufs;
    // own DMA done via final vmcnt(0)).  C/D layout: col = fr, row = fq*4 + r.
    float* sw = (float*)myslice;
    float bv[4];
#pragma unroll
    for (int nt = 0; nt < 4; nt++) bv[nt] = bias[nt * 16 + fr];
#pragma unroll
    for (int mt = 0; mt < 2; mt++) {
        int mbase = mt * 16 + fq * 4;
#pragma unroll
        for (int nt = 0; nt < 4; nt++) {
            int n = nt * 16 + fr;
#pragma unroll
            for (int r = 0; r < 4; r++)
                sw[(mbase + r) * 65 + n] = acc[mt][nt][r] + bv[nt];
        }
    }
    __syncthreads();   // the only block-wide barrier

    // epilogue: one thread per row (threads 0..127)
    if (tid < ROWS) {
        const float* rp = (const float*)(smem + (tid >> 5) * SLICE) + (tid & 31) * 65;

        // top-8 on RAW scores (exp monotone; strict > keeps ascending index
        // order among ties, matching lax.top_k)
        float tv[8]; int ti[8];
#pragma unroll
        for (int k = 0; k < 8; k++) { tv[k] = -1e30f; ti[k] = 0; }

#pragma unroll 4
        for (int e = 0; e < NEXP; e++) {
            float s = rp[e];
#pragma unroll
            for (int k = 7; k >= 1; k--) {
                bool up   = s > tv[k - 1];
                bool here = s > tv[k];
                float nv = up ? tv[k - 1] : (here ? s : tv[k]);
                int   ni = up ? ti[k - 1] : (here ? e : ti[k]);
                tv[k] = nv; ti[k] = ni;
            }
            bool c0 = s > tv[0];
            ti[0] = c0 ? e : ti[0];
            tv[0] = c0 ? s : tv[0];
        }
        float m = tv[0];   // row max

        float sum = 0.0f;
#pragma unroll 8
        for (int e = 0; e < NEXP; e++) sum += __expf(rp[e] - m);
        float rinv = 1.0f / sum;

        float wv_[8];
#pragma unroll
        for (int k = 0; k < 8; k++) wv_[k] = __expf(tv[k] - m) * rinv;

        size_t ro = (rowBase + tid) * TOPK;
        *(float4*)(out + ro)     = make_float4(wv_[0], wv_[1], wv_[2], wv_[3]);
        *(float4*)(out + ro + 4) = make_float4(wv_[4], wv_[5], wv_[6], wv_[7]);
        *(float4*)(out + OFF_IDX + ro)     = make_float4((float)ti[0], (float)ti[1], (float)ti[2], (float)ti[3]);
        *(float4*)(out + OFF_IDX + ro + 4) = make_float4((float)ti[4], (float)ti[5], (float)ti[6], (float)ti[7]);
#pragma unroll
        for (int k = 0; k < 8; k++) atomicAdd(&hist[ti[k]], 1.0f);
    }
    __syncthreads();
    if (tid < NEXP) atomicAdd(&out[OFF_USE + tid], hist[tid]);
}

extern "C" void kernel_launch(void* const* d_in, const int* in_sizes, int n_in,
                              void* d_out, int out_size, void* d_ws, size_t ws_size,
                              hipStream_t stream) {
    const float* x    = (const float*)d_in[0];
    const float* W    = (const float*)d_in[1];
    const float* bias = (const float*)d_in[2];
    float* out = (float*)d_out;
    unsigned short* wf = (unsigned short*)d_ws;   // 128 KB fragment-ordered bf16 W

    gate_prep_kernel<<<256, 256, 0, stream>>>(W, wf, out);
    gate_kernel<<<NTOK / ROWS, BLK, 0, stream>>>(x, wf, bias, out);
}